// Round 1
// baseline (221.863 us; speedup 1.0000x reference)
//
#include <hip/hip_runtime.h>
#include <hip/hip_bf16.h>

#define B_ 128
#define F_ 100
#define N_ 512
#define H_ 1024
#define P_ 512
#define E_ 8

#define BM 128
#define BN 128
#define BK 64

typedef __attribute__((ext_vector_type(8))) short bf16x8;
typedef __attribute__((ext_vector_type(4))) float f32x4;

static __device__ __forceinline__ short f2bf(float f) {
    __hip_bfloat16 h = __float2bfloat16(f);
    short s;
    __builtin_memcpy(&s, &h, sizeof(s));
    return s;
}

// W [E][R][C] fp32  ->  WT [E][C][R] bf16   (transpose + convert)
__global__ __launch_bounds__(256) void transpose_cvt(const float* __restrict__ W,
                                                     short* __restrict__ WT,
                                                     int R, int C) {
    __shared__ float tile[32][33];
    const int e = blockIdx.z;
    const int c0 = blockIdx.x * 32, r0 = blockIdx.y * 32;
    const int tx = threadIdx.x, ty = threadIdx.y;
    const float* Wp = W + (size_t)e * R * C;
    short* WTp = WT + (size_t)e * C * R;
#pragma unroll
    for (int i = 0; i < 4; i++)
        tile[ty + i * 8][tx] = Wp[(size_t)(r0 + ty + i * 8) * C + c0 + tx];
    __syncthreads();
#pragma unroll
    for (int i = 0; i < 4; i++)
        WTp[(size_t)(c0 + ty + i * 8) * R + r0 + tx] = f2bf(tile[tx][ty + i * 8]);
}

// m97-style 128x128 tile GEMM, BK=64, 4 waves 2x2, mfma_f32_16x16x32_bf16.
// FIRST:  C = x[b] @ W1T[e]^T + b1 -> softsign -> bf16 act (padded 128 rows)
// !FIRST: C = act[b] @ W2T[e]^T + b2 -> fp32 out (rows < 100)
template <int KDIM, bool FIRST>
__global__ __launch_bounds__(256, 2) void gemm_kernel(
    const float* __restrict__ x,      // FIRST: [B][F][N] fp32
    const short* __restrict__ actin,  // !FIRST: [B][128][H] bf16
    const short* __restrict__ WT,     // [E][NCOLS][KDIM] bf16 (n-major, K-contig)
    const float* __restrict__ bias,   // [E][NCOLS] fp32
    const int* __restrict__ eid,      // [B]
    short* __restrict__ actout,       // FIRST: [B][128][H] bf16
    float* __restrict__ out)          // !FIRST: [B][F][P] fp32
{
    constexpr int NCOLS = FIRST ? H_ : P_;
    __shared__ short sA[BM * BK];
    __shared__ short sB[BN * BK];
    const int b = blockIdx.y;
    const int n0 = blockIdx.x * BN;
    const int e = eid[b];
    const int t = threadIdx.x;
    const int lane = t & 63, w = t >> 6;
    const int wm = (w >> 1) * 64, wn = (w & 1) * 64;
    const int l15 = lane & 15, quad = lane >> 4;

    f32x4 acc[4][4];
#pragma unroll
    for (int mi = 0; mi < 4; mi++)
#pragma unroll
        for (int ni = 0; ni < 4; ni++)
            acc[mi][ni] = (f32x4)(0.0f);

    const short* Bt = WT + ((size_t)e * NCOLS + n0) * KDIM;

    for (int k0 = 0; k0 < KDIM; k0 += BK) {
        // ---- stage A tile [BM][BK] ----
        if constexpr (FIRST) {
            const int c4 = t & 15, r = t >> 4;
#pragma unroll
            for (int p = 0; p < 8; p++) {
                const int f = p * 16 + r;
                uint2 wv = make_uint2(0u, 0u);
                if (f < F_) {
                    const float4 v = *(const float4*)(x + ((size_t)b * F_ + f) * N_ + k0 + c4 * 4);
                    union { short s[4]; uint2 u; } tmp;
                    tmp.s[0] = f2bf(v.x); tmp.s[1] = f2bf(v.y);
                    tmp.s[2] = f2bf(v.z); tmp.s[3] = f2bf(v.w);
                    wv = tmp.u;
                }
                *(uint2*)(&sA[f * BK + c4 * 4]) = wv;
            }
        } else {
            const int c8 = t & 7, r = t >> 3;
#pragma unroll
            for (int p = 0; p < 4; p++) {
                const int f = p * 32 + r;
                const uint4 v = *(const uint4*)(actin + ((size_t)b * BM + f) * H_ + k0 + c8 * 8);
                *(uint4*)(&sA[f * BK + c8 * 8]) = v;
            }
        }
        // ---- stage B tile [BN][BK] (WT rows are K-contiguous bf16) ----
        {
            const int c8 = t & 7, r = t >> 3;
#pragma unroll
            for (int p = 0; p < 4; p++) {
                const int n = p * 32 + r;
                const uint4 v = *(const uint4*)(Bt + (size_t)n * KDIM + k0 + c8 * 8);
                *(uint4*)(&sB[n * BK + c8 * 8]) = v;
            }
        }
        __syncthreads();
#pragma unroll
        for (int ks = 0; ks < 2; ks++) {
            bf16x8 af[4], bfr[4];
#pragma unroll
            for (int mi = 0; mi < 4; mi++)
                af[mi] = *(const bf16x8*)(&sA[(wm + mi * 16 + l15) * BK + ks * 32 + quad * 8]);
#pragma unroll
            for (int ni = 0; ni < 4; ni++)
                bfr[ni] = *(const bf16x8*)(&sB[(wn + ni * 16 + l15) * BK + ks * 32 + quad * 8]);
#pragma unroll
            for (int mi = 0; mi < 4; mi++)
#pragma unroll
                for (int ni = 0; ni < 4; ni++)
                    acc[mi][ni] = __builtin_amdgcn_mfma_f32_16x16x32_bf16(af[mi], bfr[ni], acc[mi][ni], 0, 0, 0);
        }
        __syncthreads();
    }

    // ---- epilogue: C/D layout col=lane&15, row=quad*4+reg ----
#pragma unroll
    for (int mi = 0; mi < 4; mi++) {
#pragma unroll
        for (int ni = 0; ni < 4; ni++) {
            const int col = n0 + wn + ni * 16 + l15;
            const float bv = bias[(size_t)e * NCOLS + col];
#pragma unroll
            for (int r = 0; r < 4; r++) {
                const int row = wm + mi * 16 + quad * 4 + r;
                float v = acc[mi][ni][r] + bv;
                if constexpr (FIRST) {
                    v = v / (1.0f + fabsf(v));  // softsign (SCALE=1)
                    actout[((size_t)b * BM + row) * H_ + col] = f2bf(v);
                } else {
                    if (row < F_)
                        out[((size_t)b * F_ + row) * P_ + col] = v;
                }
            }
        }
    }
}

extern "C" void kernel_launch(void* const* d_in, const int* in_sizes, int n_in,
                              void* d_out, int out_size, void* d_ws, size_t ws_size,
                              hipStream_t stream) {
    const float* x  = (const float*)d_in[0];
    const int* eid  = (const int*)d_in[1];
    const float* W1 = (const float*)d_in[2];
    const float* b1 = (const float*)d_in[3];
    const float* W2 = (const float*)d_in[4];
    const float* b2 = (const float*)d_in[5];
    float* out = (float*)d_out;

    char* ws = (char*)d_ws;
    short* W1T = (short*)(ws);                         // [E][H][N] bf16 : 8 MiB
    short* W2T = (short*)(ws + (size_t)(8u << 20));    // [E][P][H] bf16 : 8 MiB
    short* act = (short*)(ws + (size_t)(16u << 20));   // [B][128][H] bf16 : 32 MiB

    transpose_cvt<<<dim3(H_ / 32, N_ / 32, E_), dim3(32, 8), 0, stream>>>(W1, W1T, N_, H_);
    transpose_cvt<<<dim3(P_ / 32, H_ / 32, E_), dim3(32, 8), 0, stream>>>(W2, W2T, H_, P_);
    gemm_kernel<N_, true><<<dim3(H_ / BN, B_), 256, 0, stream>>>(x, nullptr, W1T, b1, eid, act, nullptr);
    gemm_kernel<H_, false><<<dim3(P_ / BN, B_), 256, 0, stream>>>(nullptr, act, W2T, b2, eid, nullptr, out);
}

// Round 2
// 185.443 us; speedup vs baseline: 1.1964x; 1.1964x over previous
//
#include <hip/hip_runtime.h>
#include <hip/hip_bf16.h>

#define B_ 128
#define F_ 100
#define N_ 512
#define H_ 1024
#define P_ 512
#define E_ 8

#define BM 128
#define BK 64

typedef __attribute__((ext_vector_type(8))) short bf16x8;
typedef __attribute__((ext_vector_type(4))) float f32x4;

// async global->LDS DMA, 16B per lane, LDS dest = wave-uniform base + lane*16
#define GLOAD16(g, l) __builtin_amdgcn_global_load_lds(                      \
    (const __attribute__((address_space(1))) void*)(g),                      \
    (__attribute__((address_space(3))) void*)(l), 16, 0, 0)

static __device__ __forceinline__ short f2bf(float f) {
    __hip_bfloat16 h = __float2bfloat16(f);
    short s;
    __builtin_memcpy(&s, &h, sizeof(s));
    return s;
}

// x [B][F][N] fp32 -> xbf [B][128][N] bf16, rows F..127 zeroed.
__global__ __launch_bounds__(256) void convert_x(const float* __restrict__ x,
                                                 short* __restrict__ xbf) {
    const int g = blockIdx.x * 256 + threadIdx.x;  // one 8-elem chunk
    const int col = (g & (N_ / 8 - 1)) * 8;
    const int row = g >> 6;          // b*128 + f
    const int f = row & 127, b = row >> 7;
    union { short s[8]; uint4 u; } o;
    if (f < F_) {
        const float* xp = x + ((size_t)(b * F_ + f)) * N_ + col;
        const float4 v0 = *(const float4*)(xp);
        const float4 v1 = *(const float4*)(xp + 4);
        o.s[0] = f2bf(v0.x); o.s[1] = f2bf(v0.y);
        o.s[2] = f2bf(v0.z); o.s[3] = f2bf(v0.w);
        o.s[4] = f2bf(v1.x); o.s[5] = f2bf(v1.y);
        o.s[6] = f2bf(v1.z); o.s[7] = f2bf(v1.w);
    } else {
        o.u = make_uint4(0u, 0u, 0u, 0u);
    }
    *(uint4*)(xbf + (size_t)row * N_ + col) = o.u;
}

// W [E][R][C] fp32 -> WT [E][C][R] bf16. 64x64 tiles, 16B vector stores.
// LDS stride 65: both phases <=2-way bank aliasing (free per m136).
__global__ __launch_bounds__(256) void transpose_cvt(const float* __restrict__ W,
                                                     short* __restrict__ WT,
                                                     int R, int C) {
    __shared__ float tile[64][65];
    const int e = blockIdx.z;
    const int c0 = blockIdx.x * 64, r0 = blockIdx.y * 64;
    const int t = threadIdx.x;
    const float* Wp = W + (size_t)e * R * C;
    short* WTp = WT + (size_t)e * C * R;
    {
        const int c4 = (t & 15) * 4, r = t >> 4;  // 16 rows/pass
#pragma unroll
        for (int p = 0; p < 4; p++) {
            const int row = p * 16 + r;
            const float4 v = *(const float4*)(Wp + (size_t)(r0 + row) * C + c0 + c4);
            tile[row][c4 + 0] = v.x; tile[row][c4 + 1] = v.y;
            tile[row][c4 + 2] = v.z; tile[row][c4 + 3] = v.w;
        }
    }
    __syncthreads();
    {
        const int r8 = (t & 7) * 8, cl = t >> 3;  // cl 0..31
#pragma unroll
        for (int p = 0; p < 2; p++) {
            const int c = p * 32 + cl;
            union { short s[8]; uint4 u; } o;
#pragma unroll
            for (int j = 0; j < 8; j++) o.s[j] = f2bf(tile[r8 + j][c]);
            *(uint4*)(&WTp[(size_t)(c0 + c) * R + r0 + r8]) = o.u;
        }
    }
}

// 128xBN_ tile GEMM, BK=64, 4 waves (2x2), mfma_f32_16x16x32_bf16,
// async global_load_lds staging for both operands (A pre-converted bf16).
// FIRST:  act = softsign(A @ W1T^T + b1) -> bf16 [B][128][H]
// !FIRST: out = A @ W2T^T + b2 -> fp32 [B][F][P] (rows < F only)
template <int KDIM, int BN_, bool FIRST>
__global__ __launch_bounds__(256, 4) void gemm_kernel(
    const short* __restrict__ A,     // [B][128][KDIM] bf16, K-contig
    const short* __restrict__ WT,    // [E][NCOLS][KDIM] bf16, K-contig
    const float* __restrict__ bias,  // [E][NCOLS]
    const int* __restrict__ eid,     // [B]
    short* __restrict__ actout,      // FIRST
    float* __restrict__ out)         // !FIRST
{
    constexpr int NCOLS = FIRST ? H_ : P_;
    constexpr int NI = BN_ / 32;     // n-frags per wave
    __shared__ short sA[BM * BK];
    __shared__ short sB[BN_ * BK];
    const int b = blockIdx.y;
    const int n0 = blockIdx.x * BN_;
    const int e = eid[b];
    const int t = threadIdx.x;
    const int lane = t & 63, w = t >> 6;
    const int wm = (w >> 1) * 64, wn = (w & 1) * (BN_ / 2);
    const int l15 = lane & 15, quad = lane >> 4;
    const int lr = lane >> 3, lc = (lane & 7) * 8;  // staging: 8 rows x 64 cols per instr

    f32x4 acc[4][NI];
#pragma unroll
    for (int mi = 0; mi < 4; mi++)
#pragma unroll
        for (int ni = 0; ni < NI; ni++)
            acc[mi][ni] = (f32x4)(0.0f);

    const short* Ap = A + (size_t)b * BM * KDIM;
    const short* Bp = WT + ((size_t)e * NCOLS + n0) * KDIM;

    for (int k0 = 0; k0 < KDIM; k0 += BK) {
        // A tile: 128 rows, 32 rows per wave, 8 rows per DMA instr
#pragma unroll
        for (int i = 0; i < 4; i++) {
            const int rb = w * 32 + i * 8;
            GLOAD16(Ap + (size_t)(rb + lr) * KDIM + k0 + lc, &sA[rb * BK]);
        }
        // B tile: BN_ rows
#pragma unroll
        for (int i = 0; i < BN_ / 32; i++) {
            const int rb = w * (BN_ / 4) + i * 8;
            GLOAD16(Bp + (size_t)(rb + lr) * KDIM + k0 + lc, &sB[rb * BK]);
        }
        __syncthreads();
#pragma unroll
        for (int ks = 0; ks < 2; ks++) {
            bf16x8 af[4], bfr[NI];
#pragma unroll
            for (int mi = 0; mi < 4; mi++)
                af[mi] = *(const bf16x8*)(&sA[(wm + mi * 16 + l15) * BK + ks * 32 + quad * 8]);
#pragma unroll
            for (int ni = 0; ni < NI; ni++)
                bfr[ni] = *(const bf16x8*)(&sB[(wn + ni * 16 + l15) * BK + ks * 32 + quad * 8]);
#pragma unroll
            for (int mi = 0; mi < 4; mi++)
#pragma unroll
                for (int ni = 0; ni < NI; ni++)
                    acc[mi][ni] = __builtin_amdgcn_mfma_f32_16x16x32_bf16(af[mi], bfr[ni], acc[mi][ni], 0, 0, 0);
        }
        __syncthreads();
    }

    // epilogue: C/D layout col=lane&15, row=quad*4+reg
#pragma unroll
    for (int mi = 0; mi < 4; mi++) {
#pragma unroll
        for (int ni = 0; ni < NI; ni++) {
            const int col = n0 + wn + ni * 16 + l15;
            const float bv = bias[(size_t)e * NCOLS + col];
#pragma unroll
            for (int r = 0; r < 4; r++) {
                const int row = wm + mi * 16 + quad * 4 + r;
                float v = acc[mi][ni][r] + bv;
                if constexpr (FIRST) {
                    v = v / (1.0f + fabsf(v));  // softsign, SCALE=1
                    actout[((size_t)b * BM + row) * H_ + col] = f2bf(v);
                } else {
                    if (row < F_)
                        out[((size_t)b * F_ + row) * P_ + col] = v;
                }
            }
        }
    }
}

extern "C" void kernel_launch(void* const* d_in, const int* in_sizes, int n_in,
                              void* d_out, int out_size, void* d_ws, size_t ws_size,
                              hipStream_t stream) {
    const float* x  = (const float*)d_in[0];
    const int* eid  = (const int*)d_in[1];
    const float* W1 = (const float*)d_in[2];
    const float* b1 = (const float*)d_in[3];
    const float* W2 = (const float*)d_in[4];
    const float* b2 = (const float*)d_in[5];
    float* out = (float*)d_out;

    char* ws = (char*)d_ws;
    short* W1T = (short*)(ws);                          // [E][H][N]   8 MiB
    short* W2T = (short*)(ws + (size_t)(8u << 20));     // [E][P][H]   8 MiB
    short* act = (short*)(ws + (size_t)(16u << 20));    // [B][128][H] 32 MiB
    short* xbf = (short*)(ws + (size_t)(48u << 20));    // [B][128][N] 16 MiB

    convert_x<<<dim3((B_ * 128 * N_ / 8) / 256), 256, 0, stream>>>(x, xbf);
    transpose_cvt<<<dim3(H_ / 64, N_ / 64, E_), 256, 0, stream>>>(W1, W1T, N_, H_);
    transpose_cvt<<<dim3(P_ / 64, H_ / 64, E_), 256, 0, stream>>>(W2, W2T, H_, P_);
    gemm_kernel<N_, 128, true><<<dim3(H_ / 128, B_), 256, 0, stream>>>(xbf, W1T, b1, eid, act, nullptr);
    gemm_kernel<H_, 64, false><<<dim3(P_ / 64, B_), 256, 0, stream>>>(act, W2T, b2, eid, nullptr, out);
}

// Round 3
// 158.275 us; speedup vs baseline: 1.4018x; 1.1716x over previous
//
#include <hip/hip_runtime.h>
#include <hip/hip_bf16.h>

#define B_ 128
#define F_ 100
#define N_ 512
#define H_ 1024
#define P_ 512
#define E_ 8

#define BM 128
#define BK 64

typedef __attribute__((ext_vector_type(8))) short bf16x8;
typedef __attribute__((ext_vector_type(4))) float f32x4;

// async global->LDS DMA, 16B per lane, LDS dest = wave-uniform base + lane*16
#define GLOAD16(g, l) __builtin_amdgcn_global_load_lds(                      \
    (const __attribute__((address_space(1))) void*)(g),                      \
    (__attribute__((address_space(3))) void*)(l), 16, 0, 0)

static __device__ __forceinline__ short f2bf(float f) {
    __hip_bfloat16 h = __float2bfloat16(f);
    short s;
    __builtin_memcpy(&s, &h, sizeof(s));
    return s;
}

// Counting sort of the 128 trials by expert id. perm[pos] = original trial,
// esort[pos] = its expert. Order within an expert is nondeterministic
// (LDS atomics) but the final output is invariant to it.
__global__ __launch_bounds__(128) void sort_eid(const int* __restrict__ eid,
                                                int* __restrict__ perm,
                                                int* __restrict__ esort) {
    __shared__ int cnt[E_], base[E_];
    const int t = threadIdx.x;
    if (t < E_) cnt[t] = 0;
    __syncthreads();
    const int e = eid[t];
    atomicAdd(&cnt[e], 1);
    __syncthreads();
    if (t == 0) {
        int s = 0;
        for (int i = 0; i < E_; i++) { base[i] = s; s += cnt[i]; }
    }
    __syncthreads();
    const int pos = atomicAdd(&base[e], 1);
    perm[pos] = t;
    esort[pos] = e;
}

// x [B][F][N] fp32 -> xs [B][128][N] bf16 in SORTED trial order, pad rows 0.
__global__ __launch_bounds__(256) void convert_x(const float* __restrict__ x,
                                                 const int* __restrict__ perm,
                                                 short* __restrict__ xs) {
    const int g = blockIdx.x * 256 + threadIdx.x;  // one 8-elem chunk
    const int col = (g & (N_ / 8 - 1)) * 8;
    const int row = g >> 6;          // sp*128 + f
    const int f = row & 127, sp = row >> 7;
    union { short s[8]; uint4 u; } o;
    if (f < F_) {
        const int b = perm[sp];
        const float* xp = x + ((size_t)(b * F_ + f)) * N_ + col;
        const float4 v0 = *(const float4*)(xp);
        const float4 v1 = *(const float4*)(xp + 4);
        o.s[0] = f2bf(v0.x); o.s[1] = f2bf(v0.y);
        o.s[2] = f2bf(v0.z); o.s[3] = f2bf(v0.w);
        o.s[4] = f2bf(v1.x); o.s[5] = f2bf(v1.y);
        o.s[6] = f2bf(v1.z); o.s[7] = f2bf(v1.w);
    } else {
        o.u = make_uint4(0u, 0u, 0u, 0u);
    }
    *(uint4*)(xs + (size_t)row * N_ + col) = o.u;
}

// W [E][R][C] fp32 -> WT [E][C][R] bf16. 64x64 tiles, 16B vector stores.
__global__ __launch_bounds__(256) void transpose_cvt(const float* __restrict__ W,
                                                     short* __restrict__ WT,
                                                     int R, int C) {
    __shared__ float tile[64][65];
    const int e = blockIdx.z;
    const int c0 = blockIdx.x * 64, r0 = blockIdx.y * 64;
    const int t = threadIdx.x;
    const float* Wp = W + (size_t)e * R * C;
    short* WTp = WT + (size_t)e * C * R;
    {
        const int c4 = (t & 15) * 4, r = t >> 4;
#pragma unroll
        for (int p = 0; p < 4; p++) {
            const int row = p * 16 + r;
            const float4 v = *(const float4*)(Wp + (size_t)(r0 + row) * C + c0 + c4);
            tile[row][c4 + 0] = v.x; tile[row][c4 + 1] = v.y;
            tile[row][c4 + 2] = v.z; tile[row][c4 + 3] = v.w;
        }
    }
    __syncthreads();
    {
        const int r8 = (t & 7) * 8, cl = t >> 3;
#pragma unroll
        for (int p = 0; p < 2; p++) {
            const int c = p * 32 + cl;
            union { short s[8]; uint4 u; } o;
#pragma unroll
            for (int j = 0; j < 8; j++) o.s[j] = f2bf(tile[r8 + j][c]);
            *(uint4*)(&WTp[(size_t)(c0 + c) * R + r0 + r8]) = o.u;
        }
    }
}

// 128xBN_ tile GEMM over SORTED trials, BK=64, 4 waves (2x2),
// mfma_f32_16x16x32_bf16, async global_load_lds staging with XOR-swizzled
// LDS layout (swizzle applied on the GLOBAL address since the DMA's LDS
// destination is fixed at base + lane*16).
//   grid = (x = B_ sorted-m fastest, y = NCOLS/BN_). XCD = x%8 (round-robin
//   dispatch), remapped so XCD r owns sorted trials [16r,16r+16) -> its L2
//   holds ~1-2 experts' weights + 16 A-tiles.
// FIRST:  act = softsign(A @ W1T^T + b1) -> bf16 [sorted sp][128][H]
// !FIRST: out = A @ W2T^T + b2 -> fp32, rows scattered to perm[sp]
template <int KDIM, int BN_, bool FIRST>
__global__ __launch_bounds__(256, 4) void gemm_kernel(
    const short* __restrict__ A,     // [B][128][KDIM] bf16 sorted, K-contig
    const short* __restrict__ WT,    // [E][NCOLS][KDIM] bf16, K-contig
    const float* __restrict__ bias,  // [E][NCOLS]
    const int* __restrict__ perm,    // [B] sorted -> original trial
    const int* __restrict__ esort,   // [B] expert of sorted slot
    short* __restrict__ actout,      // FIRST
    float* __restrict__ out)         // !FIRST
{
    constexpr int NCOLS = FIRST ? H_ : P_;
    constexpr int NI = BN_ / 32;     // n-frags per wave
    __shared__ short sA[BM * BK];
    __shared__ short sB[BN_ * BK];
    const int sp = (blockIdx.x & 7) * 16 + (blockIdx.x >> 3);  // XCD-grouped
    const int n0 = blockIdx.y * BN_;
    const int e = esort[sp];
    const int t = threadIdx.x;
    const int lane = t & 63, w = t >> 6;
    const int wm = (w >> 1) * 64, wn = (w & 1) * (BN_ / 2);
    const int l15 = lane & 15, quad = lane >> 4;
    // staging: 8 rows x 64 cols per DMA instr; XOR-swizzle col-group by row
    const int lr = lane >> 3;
    const int lc = (((lane & 7) ^ lr) * 8);

    f32x4 acc[4][NI];
#pragma unroll
    for (int mi = 0; mi < 4; mi++)
#pragma unroll
        for (int ni = 0; ni < NI; ni++)
            acc[mi][ni] = (f32x4)(0.0f);

    const short* Ap = A + (size_t)sp * BM * KDIM;
    const short* Bp = WT + ((size_t)e * NCOLS + n0) * KDIM;

    for (int k0 = 0; k0 < KDIM; k0 += BK) {
#pragma unroll
        for (int i = 0; i < 4; i++) {
            const int rb = w * 32 + i * 8;
            GLOAD16(Ap + (size_t)(rb + lr) * KDIM + k0 + lc, &sA[rb * BK]);
        }
#pragma unroll
        for (int i = 0; i < BN_ / 32; i++) {
            const int rb = w * (BN_ / 4) + i * 8;
            GLOAD16(Bp + (size_t)(rb + lr) * KDIM + k0 + lc, &sB[rb * BK]);
        }
        __syncthreads();
#pragma unroll
        for (int ks = 0; ks < 2; ks++) {
            bf16x8 af[4], bfr[NI];
#pragma unroll
            for (int mi = 0; mi < 4; mi++) {
                const int ra = wm + mi * 16 + l15;
                af[mi] = *(const bf16x8*)(&sA[ra * BK + (((ks * 4 + quad) ^ (ra & 7)) * 8)]);
            }
#pragma unroll
            for (int ni = 0; ni < NI; ni++) {
                const int rbn = wn + ni * 16 + l15;
                bfr[ni] = *(const bf16x8*)(&sB[rbn * BK + (((ks * 4 + quad) ^ (rbn & 7)) * 8)]);
            }
#pragma unroll
            for (int mi = 0; mi < 4; mi++)
#pragma unroll
                for (int ni = 0; ni < NI; ni++)
                    acc[mi][ni] = __builtin_amdgcn_mfma_f32_16x16x32_bf16(af[mi], bfr[ni], acc[mi][ni], 0, 0, 0);
        }
        __syncthreads();
    }

    // epilogue: C/D layout col=lane&15, row=quad*4+reg
    const int borig = FIRST ? 0 : perm[sp];
#pragma unroll
    for (int mi = 0; mi < 4; mi++) {
#pragma unroll
        for (int ni = 0; ni < NI; ni++) {
            const int col = n0 + wn + ni * 16 + l15;
            const float bv = bias[(size_t)e * NCOLS + col];
#pragma unroll
            for (int r = 0; r < 4; r++) {
                const int row = wm + mi * 16 + quad * 4 + r;
                float v = acc[mi][ni][r] + bv;
                if constexpr (FIRST) {
                    v = v / (1.0f + fabsf(v));  // softsign, SCALE=1
                    actout[((size_t)sp * BM + row) * H_ + col] = f2bf(v);
                } else {
                    if (row < F_)
                        out[((size_t)borig * F_ + row) * P_ + col] = v;
                }
            }
        }
    }
}

extern "C" void kernel_launch(void* const* d_in, const int* in_sizes, int n_in,
                              void* d_out, int out_size, void* d_ws, size_t ws_size,
                              hipStream_t stream) {
    const float* x  = (const float*)d_in[0];
    const int* eid  = (const int*)d_in[1];
    const float* W1 = (const float*)d_in[2];
    const float* b1 = (const float*)d_in[3];
    const float* W2 = (const float*)d_in[4];
    const float* b2 = (const float*)d_in[5];
    float* out = (float*)d_out;

    char* ws = (char*)d_ws;
    short* W1T = (short*)(ws);                          // [E][H][N]   8 MiB
    short* W2T = (short*)(ws + (size_t)(8u << 20));     // [E][P][H]   8 MiB
    short* act = (short*)(ws + (size_t)(16u << 20));    // [sp][128][H] 32 MiB
    short* xs  = (short*)(ws + (size_t)(48u << 20));    // [sp][128][N] 16 MiB
    int* perm  = (int*)(ws + (size_t)(64u << 20));      // [B]
    int* esort = perm + B_;                             // [B]

    sort_eid<<<1, 128, 0, stream>>>(eid, perm, esort);
    convert_x<<<dim3((B_ * 128 * N_ / 8) / 256), 256, 0, stream>>>(x, perm, xs);
    transpose_cvt<<<dim3(H_ / 64, N_ / 64, E_), 256, 0, stream>>>(W1, W1T, N_, H_);
    transpose_cvt<<<dim3(P_ / 64, H_ / 64, E_), 256, 0, stream>>>(W2, W2T, H_, P_);
    gemm_kernel<N_, 128, true><<<dim3(B_, H_ / 128), 256, 0, stream>>>(xs, W1T, b1, perm, esort, act, nullptr);
    gemm_kernel<H_, 64, false><<<dim3(B_, P_ / 64), 256, 0, stream>>>(act, W2T, b2, perm, esort, nullptr, out);
}